// Round 1
// baseline (92.586 us; speedup 1.0000x reference)
//
#include <hip/hip_runtime.h>

#define KS 10
#define PAD 4

__device__ __forceinline__ float load_reflect(const float* __restrict__ xr, int m, int L) {
    // antireflect: xp[m] for x index m (may be out of [0,L))
    if (m < 0)   return 2.0f * xr[0]     - xr[-m];
    if (m >= L)  return 2.0f * xr[L - 1] - xr[2 * L - 2 - m];
    return xr[m];
}

// One wavelet level: depthwise stride-2 10-tap correlation with h (->a) and g (->d),
// antireflect pad depth 4. Each thread computes 4 consecutive outputs of both a and d.
// grid: (Lout/1024, rows), block: 256
__global__ __launch_bounds__(256) void dwt_level_kernel(
    const float* __restrict__ x, const float* __restrict__ hptr,
    float* __restrict__ a, float* __restrict__ d, int L) {
    const int Lout  = L >> 1;
    const int nquad = Lout >> 2;                       // output quads per row
    const int row   = blockIdx.y;
    const int i     = blockIdx.x * blockDim.x + threadIdx.x;  // quad index in row
    if (i >= nquad) return;

    // filters (uniform address -> scalar loads, broadcast)
    float h[KS], g[KS];
#pragma unroll
    for (int k = 0; k < KS; ++k) h[k] = hptr[k];
#pragma unroll
    for (int k = 0; k < KS; ++k) g[k] = ((k & 1) ? -1.0f : 1.0f) * h[KS - 1 - k];

    const float* xr = x + (size_t)row * (size_t)L;
    const int base = 8 * i - PAD;   // element offset of first needed input; 8i-4 is 16B-aligned

    float xv[20];
    if (i == 0 || i == nquad - 1) {
        // boundary thread: reflect loads (indices base..base+19 stay within reflect range)
#pragma unroll
        for (int t = 0; t < 20; ++t) xv[t] = load_reflect(xr, base + t, L);
    } else {
        const float4* p = reinterpret_cast<const float4*>(xr + base);
#pragma unroll
        for (int q = 0; q < 5; ++q) {
            float4 v = p[q];
            xv[4 * q + 0] = v.x; xv[4 * q + 1] = v.y;
            xv[4 * q + 2] = v.z; xv[4 * q + 3] = v.w;
        }
    }

    float sa[4], sd[4];
#pragma unroll
    for (int j = 0; j < 4; ++j) {
        float accA = 0.0f, accD = 0.0f;
#pragma unroll
        for (int k = 0; k < KS; ++k) {
            const float xx = xv[2 * j + k];
            accA = fmaf(xx, h[k], accA);
            accD = fmaf(xx, g[k], accD);
        }
        sa[j] = accA; sd[j] = accD;
    }

    const size_t obase = (size_t)row * (size_t)Lout + (size_t)(4 * i);
    *reinterpret_cast<float4*>(a + obase) = make_float4(sa[0], sa[1], sa[2], sa[3]);
    *reinterpret_cast<float4*>(d + obase) = make_float4(sd[0], sd[1], sd[2], sd[3]);
}

extern "C" void kernel_launch(void* const* d_in, const int* in_sizes, int n_in,
                              void* d_out, int out_size, void* d_ws, size_t ws_size,
                              hipStream_t stream) {
    (void)in_sizes; (void)n_in; (void)d_ws; (void)ws_size; (void)out_size;

    const float* signal = (const float*)d_in[0];
    const float* h      = (const float*)d_in[1];
    float* out = (float*)d_out;

    const int B = 8, C = 64, L0 = 65536, LEVELS = 4;
    const int R = B * C;  // 512 independent rows

    // output layout: signals a0..a3 then details d0..d3, each (R, L/2) flattened
    size_t s_off[4], d_off[4];
    {
        size_t off = 0;
        int L = L0;
        for (int l = 0; l < LEVELS; ++l) { s_off[l] = off; off += (size_t)R * (size_t)(L >> 1); L >>= 1; }
        L = L0;
        for (int l = 0; l < LEVELS; ++l) { d_off[l] = off; off += (size_t)R * (size_t)(L >> 1); L >>= 1; }
    }

    const float* x = signal;
    int L = L0;
    for (int l = 0; l < LEVELS; ++l) {
        const int Lout = L >> 1;
        dim3 grid(Lout / (4 * 256), R);
        dim3 block(256);
        dwt_level_kernel<<<grid, block, 0, stream>>>(x, h, out + s_off[l], out + d_off[l], L);
        x = out + s_off[l];  // next level consumes this level's approximation
        L = Lout;
    }
}